// Round 17
// baseline (226.123 us; speedup 1.0000x reference)
//
#include <hip/hip_runtime.h>

// Problem constants (from reference)
#define BB 8
#define LL 4096
#define DIM 1024
#define HH 16
#define MM 64
#define DH 64

constexpr long long NZ = (long long)BB * LL * DIM;   // 33554432
constexpr long long NG = (long long)BB * LL * HH;    // 524288
constexpr long long O_Z   = 0;
constexpr long long O_CRY = NZ;
constexpr long long O_NEW = NZ + NG;
constexpr long long O_CC  = NZ + 2 * NG;
constexpr long long O_FR  = NZ + 3 * NG;

// crystallised layout: int32 {0,1} (established R1 vs R2).
// Journal: R8 fusion regressed (346) | R9 multi-wave packing regressed (267) |
// R10 snap LDS-staging won (216) | R11 batch-burst neutral | R12 barrier-free
// snap won (210) | R13 f32-path+guard won (200.9) | R14/R15 snap levers
// exhausted (~199; snap near its ~15-20us work floor). This round: main's
// 7-stream structure (5R+2W, 4.0 TB/s logical) split into 2-stream velocity
// pass + 4-stream enforce pass (fill=6.9 TB/s 1-stream, RMSNorm=4.9 TB/s
// 2-stream on this chip -> stream count drives DRAM efficiency).

#define ROWS 8

// ---------------------------------------------------------------------------
// K1: velocity pass. Reads zc+zp (+tiny cc/cry). Writes flag outputs (6MB),
// newly-bitmask and crystal-bitmask (64KB each in d_ws).
// Velocity f64 expression + butterfly bit-identical to R2-R15.
// ---------------------------------------------------------------------------
__global__ __launch_bounds__(256) void crystal_vel(
    const float4* __restrict__ zc4,
    const float4* __restrict__ zp4,
    const int*    __restrict__ ccount, // [B*L*H] int32
    const int*    __restrict__ cryst,  // [B*L*H] int32 bool
    unsigned int* __restrict__ masks_new,
    unsigned int* __restrict__ masks_cry,
    float* __restrict__ out)
{
    __shared__ float lds_cry[ROWS * HH];
    __shared__ float lds_new[ROWS * HH];
    __shared__ float lds_cc [ROWS * HH];

    const int t   = threadIdx.x;
    const int h   = t >> 4;
    const int sub = t & 15;

    const long long row0 = (long long)blockIdx.x * ROWS;
    long long idx = row0 * (DIM / 4) + t;
    long long g   = row0 * HH + h;

    float4 zc = zc4[idx];
    float4 zp = zp4[idx];
    int    cc = ccount[g];
    int    cv = cryst[g];

    unsigned int wmask_n = 0u;   // newly bits: bit r*4 + (h&3)
    unsigned int wmask_c = 0u;   // crystal bits: same packing

    #pragma unroll
    for (int r = 0; r < ROWS; ++r) {
        const long long nidx = idx + (DIM / 4);
        const long long gn   = g + HH;
        float4 zcn, zpn; int ccn_ = 0, cvn = 0;
        if (r < ROWS - 1) {
            zcn = zc4[nidx]; zpn = zp4[nidx];
            ccn_ = ccount[gn]; cvn = cryst[gn];
        }

        // velocity^2: exact f32 diffs, f64 accumulate (bit-identical to R2-R15)
        double s;
        {
            double dx = (double)zc.x - (double)zp.x;
            double dy = (double)zc.y - (double)zp.y;
            double dz = (double)zc.z - (double)zp.z;
            double dw = (double)zc.w - (double)zp.w;
            s = dx * dx + dy * dy + dz * dz + dw * dw;
        }
        s += __shfl_xor(s, 1);
        s += __shfl_xor(s, 2);
        s += __shfl_xor(s, 4);
        s += __shfl_xor(s, 8);

        const bool conv = sqrt(s) < 0.01;   // velocity < TAU_CONVERGE
        const int  ccn  = conv ? cc + 1 : 0;
        const bool cry  = cv != 0;
        const bool newly   = (ccn >= 2) && !cry;
        const bool crystal = cry || newly;

        if (sub == 0) {
            lds_cry[r * HH + h] = crystal ? 1.0f : 0.0f;
            lds_new[r * HH + h] = newly   ? 1.0f : 0.0f;
            lds_cc [r * HH + h] = (float)ccn;
        }

        const unsigned long long baln = __ballot(newly && sub == 0);
        const unsigned int bn = (unsigned int)((baln        & 1ull)       |
                                               ((baln >> 16) & 1ull) << 1 |
                                               ((baln >> 32) & 1ull) << 2 |
                                               ((baln >> 48) & 1ull) << 3);
        wmask_n |= bn << (4 * r);

        const unsigned long long balc = __ballot(crystal && sub == 0);
        const unsigned int bc = (unsigned int)((balc        & 1ull)       |
                                               ((balc >> 16) & 1ull) << 1 |
                                               ((balc >> 32) & 1ull) << 2 |
                                               ((balc >> 48) & 1ull) << 3);
        wmask_c |= bc << (4 * r);

        zc = zcn; zp = zpn; cc = ccn_; cv = cvn;
        idx = nidx; g = gn;
    }

    if ((t & 63) == 0) {
        masks_new[blockIdx.x * 4 + (t >> 6)] = wmask_n;
        masks_cry[blockIdx.x * 4 + (t >> 6)] = wmask_c;
    }

    __syncthreads();
    if (t < ROWS * HH) {
        const long long g0 = (long long)blockIdx.x * (ROWS * HH) + t;
        out[O_CRY + g0] = lds_cry[t];
        out[O_NEW + g0] = lds_new[t];
        out[O_CC  + g0] = lds_cc [t];
    }
}

// ---------------------------------------------------------------------------
// K2: enforce pass. Reads zc+fr (+L2-hot crystal bitmask). Writes O_Z+O_FR.
// zout = crystal ? fr : zc — identical selection to R8-R15 main.
// ---------------------------------------------------------------------------
__global__ __launch_bounds__(256) void crystal_enf(
    const float4* __restrict__ zc4,
    const float4* __restrict__ fr4,
    const unsigned int* __restrict__ masks_cry,
    float* __restrict__ out)
{
    const int t  = threadIdx.x;
    const int h2 = (t >> 4) & 3;       // head within wave
    const int wv = t >> 6;

    const unsigned int cw = masks_cry[blockIdx.x * 4 + wv];

    const long long row0 = (long long)blockIdx.x * ROWS;
    long long idx = row0 * (DIM / 4) + t;

    float4 zc = zc4[idx];
    float4 fr = fr4[idx];

    #pragma unroll
    for (int r = 0; r < ROWS; ++r) {
        const long long nidx = idx + (DIM / 4);
        float4 zcn, frn;
        if (r < ROWS - 1) { zcn = zc4[nidx]; frn = fr4[nidx]; }

        const bool crystal = (cw >> (4 * r + h2)) & 1u;

        float4 zout;
        zout.x = crystal ? fr.x : zc.x;
        zout.y = crystal ? fr.y : zc.y;
        zout.z = crystal ? fr.z : zc.z;
        zout.w = crystal ? fr.w : zc.w;

        reinterpret_cast<float4*>(out + O_Z)[idx]  = zout;
        reinterpret_cast<float4*>(out + O_FR)[idx] = fr;

        zc = zcn; fr = frn; idx = nidx;
    }
}

// ---------------------------------------------------------------------------
// K3: codebook snap (R15 verbatim: barrier-free one-wave blocks, LDS codebook,
// f32 fast path + guarded exact-f64 fallback, depth-2 z prefetch).
// ---------------------------------------------------------------------------
#define MB_PER_CHUNK 8                     // main-blocks per snap block
#define CHUNK_ROWS  (MB_PER_CHUNK * ROWS)  // 64
#define NCHUNKS     (BB * LL / CHUNK_ROWS) // 512
#define CBPAD 68                           // 17 float4/row: b128-aligned rows

__global__ __launch_bounds__(64) void crystal_snap(
    const float4* __restrict__ zc4,
    const float*  __restrict__ cb,     // [H][M][DH]
    const unsigned int* __restrict__ masks,
    float* __restrict__ out)
{
    __shared__ float cbl[MM * CBPAD];
    __shared__ float zl[2][DH];

    const int lane = threadIdx.x;              // 0..63 = code index
    const int h    = blockIdx.x / NCHUNKS;     // h-major
    const int c    = blockIdx.x % NCHUNKS;
    const int w    = h >> 2;
    const int h2   = h & 3;

    const int mb = c * MB_PER_CHUNK + lane;
    const unsigned int word = (lane < MB_PER_CHUNK) ? masks[mb * 4 + w] : 0u;
    unsigned int rows8 = 0u;
    #pragma unroll
    for (int r = 0; r < ROWS; ++r)
        rows8 |= ((word >> (4 * r + h2)) & 1u) << r;

    unsigned long long act = __ballot(rows8 != 0u);
    if (act == 0ull) return;

    int curl = 0; unsigned int curm8 = 0u;
    auto next_bl = [&]() -> long long {
        while (curm8 == 0u) {
            if (act == 0ull) return -1;
            curl = __ffsll(act) - 1; act &= act - 1;
            curm8 = __shfl(rows8, curl);
        }
        const int r = __ffs(curm8) - 1; curm8 &= curm8 - 1;
        return (long long)(c * MB_PER_CHUNK + curl) * ROWS + r;
    };

    long long bl0 = next_bl();
    long long seg0 = bl0 * (DIM / 4) + h * (DH / 4);
    float4 zv0;
    if (lane < 16) zv0 = zc4[seg0 + lane];

    const float4* cbh4 = reinterpret_cast<const float4*>(cb + (long long)h * MM * DH);
    #pragma unroll
    for (int i = 0; i < 16; ++i) {
        const int gidx = i * 64 + lane;
        const float4 v = cbh4[gidx];
        const int m  = gidx >> 4;
        const int k4 = (gidx & 15) * 4;
        float* dst = &cbl[m * CBPAD + k4];
        dst[0] = v.x; dst[1] = v.y; dst[2] = v.z; dst[3] = v.w;
    }

    long long bl1 = next_bl();
    long long seg1 = bl1 * (DIM / 4) + h * (DH / 4);
    float4 zv1;
    if (bl1 >= 0 && lane < 16) zv1 = zc4[seg1 + lane];

    float4 crw[16];
    #pragma unroll
    for (int k = 0; k < 16; ++k)
        crw[k] = *reinterpret_cast<const float4*>(&cbl[lane * CBPAD + k * 4]);

    int p = 0;

    while (bl0 >= 0) {
        if (lane < 16) reinterpret_cast<float4*>(zl[p])[lane] = zv0;

        const long long bl2 = next_bl();
        const long long seg2 = bl2 * (DIM / 4) + h * (DH / 4);
        float4 zv2;
        if (bl2 >= 0 && lane < 16) zv2 = zc4[seg2 + lane];

        float f0 = 0.f, f1 = 0.f, f2 = 0.f, f3 = 0.f;
        #pragma unroll
        for (int k = 0; k < 16; ++k) {
            const float4 zk = reinterpret_cast<const float4*>(zl[p])[k];
            const float q0 = zk.x - crw[k].x;
            const float q1 = zk.y - crw[k].y;
            const float q2 = zk.z - crw[k].z;
            const float q3 = zk.w - crw[k].w;
            f0 += q0 * q0; f1 += q1 * q1; f2 += q2 * q2; f3 += q3 * q3;
        }
        float b1 = (f0 + f1) + (f2 + f3);
        int   i1 = lane;
        float b2 = 3.4e38f;
        #pragma unroll
        for (int m2 = 1; m2 <= 32; m2 <<= 1) {
            const float ob1 = __shfl_xor(b1, m2);
            const int   oi1 = __shfl_xor(i1, m2);
            const float ob2 = __shfl_xor(b2, m2);
            const bool take = (ob1 < b1) || (ob1 == b1 && oi1 < i1);
            const float loser = take ? b1 : ob1;
            if (take) { b1 = ob1; i1 = oi1; }
            b2 = fminf(fminf(b2, ob2), loser);
        }
        int bidx = i1;

        if (b2 - b1 <= 1e-3f) {
            const float* crow = &cbl[lane * CBPAD];
            const float* zrow = zl[p];
            double a0 = 0.0, a1 = 0.0, a2 = 0.0, a3 = 0.0;
            #pragma unroll
            for (int d = 0; d < DH; d += 4) {
                double q0 = (double)zrow[d + 0] - (double)crow[d + 0];
                double q1 = (double)zrow[d + 1] - (double)crow[d + 1];
                double q2 = (double)zrow[d + 2] - (double)crow[d + 2];
                double q3 = (double)zrow[d + 3] - (double)crow[d + 3];
                a0 += q0 * q0; a1 += q1 * q1; a2 += q2 * q2; a3 += q3 * q3;
            }
            double best = (a0 + a1) + (a2 + a3);
            int bx = lane;
            #pragma unroll
            for (int m2 = 1; m2 <= 32; m2 <<= 1) {
                double ob = __shfl_xor(best, m2);
                int    oi = __shfl_xor(bx, m2);
                if (ob < best || (ob == best && oi < bx)) { best = ob; bx = oi; }
            }
            bidx = bx;
        }

        if (lane < 16) {
            const float* er = &cbl[bidx * CBPAD + lane * 4];
            float4 ev;
            ev.x = er[0]; ev.y = er[1]; ev.z = er[2]; ev.w = er[3];
            reinterpret_cast<float4*>(out + O_Z)[seg0 + lane]  = ev;
            reinterpret_cast<float4*>(out + O_FR)[seg0 + lane] = ev;
        }

        bl0 = bl1; seg0 = seg1; zv0 = zv1;
        bl1 = bl2; seg1 = seg2; zv1 = zv2;
        p ^= 1;
    }
}

extern "C" void kernel_launch(void* const* d_in, const int* in_sizes, int n_in,
                              void* d_out, int out_size, void* d_ws, size_t ws_size,
                              hipStream_t stream) {
    const float4* zc4 = (const float4*)d_in[0];
    const float4* zp4 = (const float4*)d_in[1];
    const float*  cb  = (const float*)d_in[2];
    const float4* fr4 = (const float4*)d_in[3];
    const int*    cc  = (const int*)d_in[4];
    const int*    cry = (const int*)d_in[5];
    float* out = (float*)d_out;
    unsigned int* masks_new = (unsigned int*)d_ws;           // 64KB
    unsigned int* masks_cry = (unsigned int*)d_ws + 16384;   // 64KB

    hipLaunchKernelGGL(crystal_vel, dim3((BB * LL) / ROWS), dim3(256), 0, stream,
                       zc4, zp4, cc, cry, masks_new, masks_cry, out);
    hipLaunchKernelGGL(crystal_enf, dim3((BB * LL) / ROWS), dim3(256), 0, stream,
                       zc4, fr4, masks_cry, out);
    hipLaunchKernelGGL(crystal_snap, dim3(HH * NCHUNKS), dim3(64), 0, stream,
                       zc4, cb, masks_new, out);
}

// Round 18
// 198.793 us; speedup vs baseline: 1.1375x; 1.1375x over previous
//
#include <hip/hip_runtime.h>

// Problem constants (from reference)
#define BB 8
#define LL 4096
#define DIM 1024
#define HH 16
#define MM 64
#define DH 64

// Flat sizes / output offsets (outputs concatenated, read back as f32)
constexpr long long NZ = (long long)BB * LL * DIM;   // 33554432
constexpr long long NG = (long long)BB * LL * HH;    // 524288
constexpr long long O_Z   = 0;
constexpr long long O_CRY = NZ;
constexpr long long O_NEW = NZ + NG;
constexpr long long O_CC  = NZ + 2 * NG;
constexpr long long O_FR  = NZ + 3 * NG;

// crystallised layout: int32 {0,1} (established empirically R1 vs R2).
// Journal: R8 fusion regressed (346) | R9 multi-wave packing regressed (267) |
// R10 snap LDS-staging won (216) | R11 batch-burst neutral | R12 barrier-free
// snap won (210) | R13 f32-path + guarded fallback won (200.9) | R14 chunk=8
// won slightly (198.8, BEST) | R15 threshold+depth2 neutral (199.0) | R16
// stream-split REGRESSED (226): K1+K2 ran at the same ~4.0 TB/s as the
// 7-stream main -> stream count does NOT drive the plateau; ~4.1 TB/s is this
// chip's rate for this f32 mixed-R/W streaming pattern across ALL tested
// structures. Composed floor ~185-195us; this kernel = 198.8us. REVERTED to
// best-known (R14/R15 structure).

// ---------------------------------------------------------------------------
// Phase 1: pure streaming (R8 verbatim; 158-167us across ten measurements).
// ---------------------------------------------------------------------------
#define ROWS 8

__global__ __launch_bounds__(256) void crystal_main(
    const float4* __restrict__ zc4,
    const float4* __restrict__ zp4,
    const float4* __restrict__ fr4,
    const int*    __restrict__ ccount, // [B*L*H] int32
    const int*    __restrict__ cryst,  // [B*L*H] int32 bool
    unsigned int* __restrict__ masks,  // [gridDim*4] newly bitmasks
    float* __restrict__ out)
{
    __shared__ float lds_cry[ROWS * HH];
    __shared__ float lds_new[ROWS * HH];
    __shared__ float lds_cc [ROWS * HH];

    const int t   = threadIdx.x;
    const int h   = t >> 4;
    const int sub = t & 15;

    const long long row0 = (long long)blockIdx.x * ROWS;
    long long idx = row0 * (DIM / 4) + t;
    long long g   = row0 * HH + h;

    float4 zc = zc4[idx];
    float4 zp = zp4[idx];
    float4 fr = fr4[idx];
    int    cc = ccount[g];
    int    cv = cryst[g];

    unsigned int wmask = 0u;   // newly bits for this wave: bit r*4 + (h&3)

    #pragma unroll
    for (int r = 0; r < ROWS; ++r) {
        // ---- prefetch next row (full unroll -> compiler hoists loads) ----
        const long long nidx = idx + (DIM / 4);
        const long long gn   = g + HH;
        float4 zcn, zpn, frn; int ccn_ = 0, cvn = 0;
        if (r < ROWS - 1) {
            zcn = zc4[nidx]; zpn = zp4[nidx]; frn = fr4[nidx];
            ccn_ = ccount[gn]; cvn = cryst[gn];
        }

        // velocity^2: exact f32 diffs, f64 accumulate (bit-identical to R2-R16)
        double s;
        {
            double dx = (double)zc.x - (double)zp.x;
            double dy = (double)zc.y - (double)zp.y;
            double dz = (double)zc.z - (double)zp.z;
            double dw = (double)zc.w - (double)zp.w;
            s = dx * dx + dy * dy + dz * dz + dw * dw;
        }
        s += __shfl_xor(s, 1);
        s += __shfl_xor(s, 2);
        s += __shfl_xor(s, 4);
        s += __shfl_xor(s, 8);

        const bool conv = sqrt(s) < 0.01;   // velocity < TAU_CONVERGE
        const int  ccn  = conv ? cc + 1 : 0;
        const bool cry  = cv != 0;
        const bool newly   = (ccn >= 2) && !cry;
        const bool crystal = cry || newly;

        float4 zout;
        zout.x = crystal ? fr.x : zc.x;
        zout.y = crystal ? fr.y : zc.y;
        zout.z = crystal ? fr.z : zc.z;
        zout.w = crystal ? fr.w : zc.w;

        reinterpret_cast<float4*>(out + O_Z)[idx]  = zout;
        reinterpret_cast<float4*>(out + O_FR)[idx] = fr;

        if (sub == 0) {
            lds_cry[r * HH + h] = crystal ? 1.0f : 0.0f;
            lds_new[r * HH + h] = newly   ? 1.0f : 0.0f;
            lds_cc [r * HH + h] = (float)ccn;
        }

        // newly bitmask: ballot has bits only at lanes 0,16,32,48 of the wave
        const unsigned long long bal = __ballot(newly && sub == 0);
        const unsigned int b4 = (unsigned int)((bal        & 1ull)       |
                                               ((bal >> 16) & 1ull) << 1 |
                                               ((bal >> 32) & 1ull) << 2 |
                                               ((bal >> 48) & 1ull) << 3);
        wmask |= b4 << (4 * r);

        zc = zcn; zp = zpn; fr = frn; cc = ccn_; cv = cvn;
        idx = nidx; g = gn;
    }

    if ((t & 63) == 0)
        masks[blockIdx.x * 4 + (t >> 6)] = wmask;

    __syncthreads();
    // coalesced 512B flag writes (block's g-range is contiguous: blockIdx*128)
    if (t < ROWS * HH) {
        const long long g0 = (long long)blockIdx.x * (ROWS * HH) + t;
        out[O_CRY + g0] = lds_cry[t];
        out[O_NEW + g0] = lds_new[t];
        out[O_CC  + g0] = lds_cc [t];
    }
}

// ---------------------------------------------------------------------------
// Phase 2: codebook snap. Barrier-free one-wave blocks (R12), LDS codebook +
// code row in registers + f32 fast path + guarded exact-f64 fallback (R13),
// MB_PER_CHUNK=8 (R14), depth-2 z prefetch (R15).
// ---------------------------------------------------------------------------
#define MB_PER_CHUNK 8                     // main-blocks per snap block
#define CHUNK_ROWS  (MB_PER_CHUNK * ROWS)  // 64
#define NCHUNKS     (BB * LL / CHUNK_ROWS) // 512
#define CBPAD 68                           // 17 float4/row: b128-aligned rows

__global__ __launch_bounds__(64) void crystal_snap(
    const float4* __restrict__ zc4,
    const float*  __restrict__ cb,     // [H][M][DH]
    const unsigned int* __restrict__ masks,
    float* __restrict__ out)
{
    __shared__ float cbl[MM * CBPAD];   // 17.4KB padded codebook
    __shared__ float zl[2][DH];         // double-buffered z row segment

    const int lane = threadIdx.x;              // 0..63 = code index
    const int h    = blockIdx.x / NCHUNKS;     // h-major
    const int c    = blockIdx.x % NCHUNKS;
    const int w    = h >> 2;                   // wave slot within main block
    const int h2   = h & 3;                    // bit sub-position

    // my main-block's 8-row newly mask for head h (lanes >= MB_PER_CHUNK idle)
    const int mb = c * MB_PER_CHUNK + lane;
    const unsigned int word = (lane < MB_PER_CHUNK) ? masks[mb * 4 + w] : 0u;
    unsigned int rows8 = 0u;
    #pragma unroll
    for (int r = 0; r < ROWS; ++r)
        rows8 |= ((word >> (4 * r + h2)) & 1u) << r;

    unsigned long long act = __ballot(rows8 != 0u);
    if (act == 0ull) return;

    // uniform work-item iterator over (lane, row) bits
    int curl = 0; unsigned int curm8 = 0u;
    auto next_bl = [&]() -> long long {
        while (curm8 == 0u) {
            if (act == 0ull) return -1;
            curl = __ffsll(act) - 1; act &= act - 1;
            curm8 = __shfl(rows8, curl);
        }
        const int r = __ffs(curm8) - 1; curm8 &= curm8 - 1;
        return (long long)(c * MB_PER_CHUNK + curl) * ROWS + r;
    };

    // item 0's z load issued BEFORE staging (overlaps the codebook load)
    long long bl0 = next_bl();
    long long seg0 = bl0 * (DIM / 4) + h * (DH / 4);
    float4 zv0;
    if (lane < 16) zv0 = zc4[seg0 + lane];     // lane k holds z chunk k

    // ---- coalesced codebook load -> padded LDS (same wave writes & reads) ----
    const float4* cbh4 = reinterpret_cast<const float4*>(cb + (long long)h * MM * DH);
    #pragma unroll
    for (int i = 0; i < 16; ++i) {
        const int gidx = i * 64 + lane;        // float4 index within head
        const float4 v = cbh4[gidx];
        const int m  = gidx >> 4;
        const int k4 = (gidx & 15) * 4;
        float* dst = &cbl[m * CBPAD + k4];
        dst[0] = v.x; dst[1] = v.y; dst[2] = v.z; dst[3] = v.w;
    }

    // item 1's z load (depth-2 pipeline established)
    long long bl1 = next_bl();
    long long seg1 = bl1 * (DIM / 4) + h * (DH / 4);
    float4 zv1;
    if (bl1 >= 0 && lane < 16) zv1 = zc4[seg1 + lane];

    // my code row -> registers (16 x b128 from LDS, once per block)
    float4 crw[16];
    #pragma unroll
    for (int k = 0; k < 16; ++k)
        crw[k] = *reinterpret_cast<const float4*>(&cbl[lane * CBPAD + k * 4]);

    int p = 0;

    while (bl0 >= 0) {
        if (lane < 16) reinterpret_cast<float4*>(zl[p])[lane] = zv0;

        // prefetch item i+2 — two loads in flight through this item's compute
        const long long bl2 = next_bl();
        const long long seg2 = bl2 * (DIM / 4) + h * (DH / 4);
        float4 zv2;
        if (bl2 >= 0 && lane < 16) zv2 = zc4[seg2 + lane];

        // ---- f32 fast path: distance from registers, z broadcast b128 ----
        float f0 = 0.f, f1 = 0.f, f2 = 0.f, f3 = 0.f;
        #pragma unroll
        for (int k = 0; k < 16; ++k) {
            const float4 zk = reinterpret_cast<const float4*>(zl[p])[k];
            const float q0 = zk.x - crw[k].x;
            const float q1 = zk.y - crw[k].y;
            const float q2 = zk.z - crw[k].z;
            const float q3 = zk.w - crw[k].w;
            f0 += q0 * q0; f1 += q1 * q1; f2 += q2 * q2; f3 += q3 * q3;
        }
        float b1 = (f0 + f1) + (f2 + f3);
        int   i1 = lane;
        float b2 = 3.4e38f;
        #pragma unroll
        for (int m2 = 1; m2 <= 32; m2 <<= 1) {
            const float ob1 = __shfl_xor(b1, m2);
            const int   oi1 = __shfl_xor(i1, m2);
            const float ob2 = __shfl_xor(b2, m2);
            const bool take = (ob1 < b1) || (ob1 == b1 && oi1 < i1);
            const float loser = take ? b1 : ob1;
            if (take) { b1 = ob1; i1 = oi1; }
            b2 = fminf(fminf(b2, ob2), loser);
        }
        int bidx = i1;

        // ---- guarded exact fallback (wave-uniform; f32 abs error <=~1.2e-4,
        //      threshold 1e-3 keeps 8x margin) ----
        if (b2 - b1 <= 1e-3f) {
            const float* crow = &cbl[lane * CBPAD];
            const float* zrow = zl[p];
            double a0 = 0.0, a1 = 0.0, a2 = 0.0, a3 = 0.0;
            #pragma unroll
            for (int d = 0; d < DH; d += 4) {
                double q0 = (double)zrow[d + 0] - (double)crow[d + 0];
                double q1 = (double)zrow[d + 1] - (double)crow[d + 1];
                double q2 = (double)zrow[d + 2] - (double)crow[d + 2];
                double q3 = (double)zrow[d + 3] - (double)crow[d + 3];
                a0 += q0 * q0; a1 += q1 * q1; a2 += q2 * q2; a3 += q3 * q3;
            }
            double best = (a0 + a1) + (a2 + a3);
            int bx = lane;
            #pragma unroll
            for (int m2 = 1; m2 <= 32; m2 <<= 1) {
                double ob = __shfl_xor(best, m2);
                int    oi = __shfl_xor(bx, m2);
                if (ob < best || (ob == best && oi < bx)) { best = ob; bx = oi; }
            }
            bidx = bx;
        }

        if (lane < 16) {
            const float* er = &cbl[bidx * CBPAD + lane * 4];
            float4 ev;
            ev.x = er[0]; ev.y = er[1]; ev.z = er[2]; ev.w = er[3];
            reinterpret_cast<float4*>(out + O_Z)[seg0 + lane]  = ev;
            reinterpret_cast<float4*>(out + O_FR)[seg0 + lane] = ev;
        }

        // rotate depth-2 pipeline
        bl0 = bl1; seg0 = seg1; zv0 = zv1;
        bl1 = bl2; seg1 = seg2; zv1 = zv2;
        p ^= 1;
    }
}

extern "C" void kernel_launch(void* const* d_in, const int* in_sizes, int n_in,
                              void* d_out, int out_size, void* d_ws, size_t ws_size,
                              hipStream_t stream) {
    const float4* zc4 = (const float4*)d_in[0];
    const float4* zp4 = (const float4*)d_in[1];
    const float*  cb  = (const float*)d_in[2];
    const float4* fr4 = (const float4*)d_in[3];
    const int*    cc  = (const int*)d_in[4];
    const int*    cry = (const int*)d_in[5];
    float* out = (float*)d_out;
    unsigned int* masks = (unsigned int*)d_ws;   // 64KB of scratch

    hipLaunchKernelGGL(crystal_main, dim3((BB * LL) / ROWS), dim3(256), 0, stream,
                       zc4, zp4, fr4, cc, cry, masks, out);
    hipLaunchKernelGGL(crystal_snap, dim3(HH * NCHUNKS), dim3(64), 0, stream,
                       zc4, cb, masks, out);
}